// Round 1
// baseline (169.927 us; speedup 1.0000x reference)
//
#include <hip/hip_runtime.h>

#define T_LEN 2048
#define NMODE 8
#define NPP   17   // 8 tau + 9 g

// ---------------------------------------------------------------------------
// Phase 1 (PHASE3=false): per (b, chunk, entry) run the 8-mode recurrence from
//   zero state over L steps; emit R[b,c,m,e] (chunk result from zero) and
//   P[b,c,m] (product of A over the chunk; entry-independent, e==0 writes).
// Phase 3 (PHASE3=true): R holds per-chunk initial states Z (after chunk_scan);
//   rerun recurrence from Z and write S, S_infy, Q_sum.
// ---------------------------------------------------------------------------
template <bool PHASE3>
__global__ __launch_bounds__(256)
void scan_phase(const float* __restrict__ Se,   // [B,T,3,3]
                const float* __restrict__ tt,   // [B,T]
                const float* __restrict__ pp,   // [B,T,17]
                float* __restrict__ R,          // [B,NC,8,9]
                float* __restrict__ P,          // [B,NC,8]
                float* __restrict__ out,        // [3,B,T,3,3] (phase3)
                int B, int NC, int L) {
    int tid = blockIdx.x * blockDim.x + threadIdx.x;
    int total = B * NC * 9;
    if (tid >= total) return;
    int e  = tid % 9;
    int bc = tid / 9;
    int c  = bc % NC;
    int b  = bc / NC;
    int t0 = c * L;

    // ---- previous-row state at chunk start ----
    float raw[NPP];
    {
        int prow = (t0 == 0) ? 0 : (t0 - 1);
        const float* p = pp + ((size_t)b * T_LEN + prow) * NPP;
        #pragma unroll
        for (int k = 0; k < NPP; ++k) raw[k] = p[k];
    }
    float gs = 0.f;
    #pragma unroll
    for (int k = 8; k < NPP; ++k) gs += raw[k];
    float inv = 1.0f / gs;

    float tau_p[NMODE], g_p[NMODE];
    #pragma unroll
    for (int m = 0; m < NMODE; ++m) {
        tau_p[m] = raw[m];
        g_p[m]   = raw[9 + m] * inv;
    }
    float t_p = (t0 == 0) ? -tt[(size_t)b * T_LEN + 1]
                          :  tt[(size_t)b * T_LEN + t0 - 1];
    float S_p = (t0 == 0) ? 0.f
                          : Se[((size_t)b * T_LEN + t0 - 1) * 9 + e];

    // ---- recurrence state ----
    size_t ridx = (((size_t)b * NC + c) * NMODE) * 9 + (size_t)e;
    float Q[NMODE], Pp[NMODE];
    #pragma unroll
    for (int m = 0; m < NMODE; ++m) {
        Q[m]  = PHASE3 ? R[ridx + (size_t)m * 9] : 0.f;
        Pp[m] = 1.0f;
    }

    const size_t nOut = (size_t)B * T_LEN * 9;

    for (int s = 0; s < L; ++s) {
        int trow = t0 + s;
        const float* p = pp + ((size_t)b * T_LEN + trow) * NPP;
        #pragma unroll
        for (int k = 0; k < NPP; ++k) raw[k] = p[k];

        float gs2 = 0.f;
        #pragma unroll
        for (int k = 8; k < NPP; ++k) gs2 += raw[k];
        float inv2 = 1.0f / gs2;

        float t_c = tt[(size_t)b * T_LEN + trow];
        size_t sidx = ((size_t)b * T_LEN + trow) * 9 + (size_t)e;
        float S_c = Se[sidx];

        float dtv = t_c - t_p;
        float dS  = S_c - S_p;
        float mhdt = -0.5f * dtv;

        float qsum = 0.f;
        #pragma unroll
        for (int m = 0; m < NMODE; ++m) {
            float tau_c  = raw[m];
            float g_c    = raw[9 + m] * inv2;
            float tau_b  = 0.5f * (tau_c + tau_p[m]);
            float g_b    = 0.5f * (g_c + g_p[m]);
            float ee     = __expf(mhdt / tau_b);
            float A      = ee * ee;
            Q[m] = A * Q[m] + (ee * g_b) * dS;
            if (!PHASE3) Pp[m] *= A;
            else         qsum  += Q[m];
            tau_p[m] = tau_c;
            g_p[m]   = g_c;
        }
        t_p = t_c;
        S_p = S_c;

        if (PHASE3) {
            float sinf = (raw[8] * inv2) * S_c;
            out[sidx]            = sinf + qsum;  // S
            out[nOut + sidx]     = sinf;         // S_infy
            out[2 * nOut + sidx] = qsum;         // Q_sum
        }
    }

    if (!PHASE3) {
        #pragma unroll
        for (int m = 0; m < NMODE; ++m) R[ridx + (size_t)m * 9] = Q[m];
        if (e == 0) {
            size_t pidx = ((size_t)b * NC + c) * NMODE;
            #pragma unroll
            for (int m = 0; m < NMODE; ++m) P[pidx + m] = Pp[m];
        }
    }
}

// ---------------------------------------------------------------------------
// Phase 2: per (b, mode, entry) sequential exclusive scan over NC chunk
// transforms; rewrites R[b,c,m,e] to Z (state entering chunk c).
// ---------------------------------------------------------------------------
__global__ __launch_bounds__(256)
void chunk_scan(float* __restrict__ R, const float* __restrict__ P,
                int B, int NC) {
    int tid = blockIdx.x * blockDim.x + threadIdx.x;
    int total = B * NMODE * 9;
    if (tid >= total) return;
    int e = tid % 9;
    int m = (tid / 9) % NMODE;
    int b = tid / (NMODE * 9);

    float z = 0.f;
    for (int c = 0; c < NC; ++c) {
        size_t ridx = (((size_t)b * NC + c) * NMODE + m) * 9 + (size_t)e;
        size_t pidx = ((size_t)b * NC + c) * NMODE + m;
        float r = R[ridx];
        float p = P[pidx];
        R[ridx] = z;            // Z for chunk c
        z = p * z + r;          // state entering chunk c+1
    }
}

extern "C" void kernel_launch(void* const* d_in, const int* in_sizes, int n_in,
                              void* d_out, int out_size, void* d_ws, size_t ws_size,
                              hipStream_t stream) {
    const float* Se = (const float*)d_in[0];
    const float* tt = (const float*)d_in[1];
    const float* pp = (const float*)d_in[2];
    float* out = (float*)d_out;

    int B = in_sizes[1] / T_LEN;

    // Pick the largest chunk count whose state fits in the workspace.
    int NC = 128;
    while (NC > 1) {
        size_t need = (size_t)B * NC * NMODE * 9 * sizeof(float)   // R
                    + (size_t)B * NC * NMODE * sizeof(float);      // P
        if (need <= ws_size) break;
        NC >>= 1;
    }
    int L = T_LEN / NC;

    float* R = (float*)d_ws;
    float* P = R + (size_t)B * NC * NMODE * 9;

    dim3 blk(256);
    int tot1 = B * NC * 9;
    int grid1 = (tot1 + 255) / 256;
    scan_phase<false><<<grid1, blk, 0, stream>>>(Se, tt, pp, R, P, nullptr, B, NC, L);

    int tot2 = B * NMODE * 9;
    int grid2 = (tot2 + 255) / 256;
    chunk_scan<<<grid2, blk, 0, stream>>>(R, P, B, NC);

    scan_phase<true><<<grid1, blk, 0, stream>>>(Se, tt, pp, R, P, out, B, NC, L);
}

// Round 2
// 135.883 us; speedup vs baseline: 1.2505x; 1.2505x over previous
//
#include <hip/hip_runtime.h>

#define T_LEN 2048
#define NMODE 8
#define NPP   17   // 8 tau + 9 g

// ---------------------------------------------------------------------------
// Coefficient precompute: one thread per (b,t).
//   A[m]  = e*e,  C[m] = e*g_bar,  e = exp(-0.5*dt/tau_bar)
//   GI    = g[0]/sum(g)  (for S_infy)
// AC layout: [B*T, 16] = A[0..7], C[0..7]  (64B-aligned rows)
// ---------------------------------------------------------------------------
__global__ __launch_bounds__(256)
void coeff_kernel(const float* __restrict__ tt,
                  const float* __restrict__ pp,
                  float* __restrict__ AC,
                  float* __restrict__ GI,
                  int B) {
    int tid = blockIdx.x * blockDim.x + threadIdx.x;
    int total = B * T_LEN;
    if (tid >= total) return;
    int t = tid % T_LEN;
    int b = tid / T_LEN;
    size_t row  = (size_t)b * T_LEN + t;
    size_t prow = (t == 0) ? row : row - 1;

    float cur[NPP], prv[NPP];
    const float* pc = pp + row  * NPP;
    const float* pv = pp + prow * NPP;
    #pragma unroll
    for (int k = 0; k < NPP; ++k) { cur[k] = pc[k]; prv[k] = pv[k]; }

    float sc = 0.f, sp = 0.f;
    #pragma unroll
    for (int k = 8; k < NPP; ++k) { sc += cur[k]; sp += prv[k]; }
    float ic = __builtin_amdgcn_rcpf(sc);
    float ip = __builtin_amdgcn_rcpf(sp);

    float t_c = tt[row];
    float t_p = (t == 0) ? -tt[(size_t)b * T_LEN + 1] : tt[row - 1];
    float mhdt = -0.5f * (t_c - t_p);

    float* o = AC + row * 16;
    #pragma unroll
    for (int m = 0; m < NMODE; ++m) {
        float tau_b = 0.5f * (cur[m] + prv[m]);
        float g_b   = 0.5f * (cur[9 + m] * ic + prv[9 + m] * ip);
        float ee    = __expf(mhdt * __builtin_amdgcn_rcpf(tau_b));
        o[m]     = ee * ee;
        o[8 + m] = ee * g_b;
    }
    GI[row] = cur[8] * ic;
}

// ---------------------------------------------------------------------------
// Scan phases using precomputed coefficients.
// R layout: [b, m, e, NC]  -> (((b*8+m)*9+e)*NC + c)
// P layout: [b, m, NC]     -> ((b*8+m)*NC + c)
// ---------------------------------------------------------------------------
template <bool PHASE3>
__global__ __launch_bounds__(256)
void scan_coeff(const float* __restrict__ Se,
                const float* __restrict__ AC,
                const float* __restrict__ GI,
                float* __restrict__ R,
                float* __restrict__ P,
                float* __restrict__ out,
                int B, int NC, int L) {
    int tid = blockIdx.x * blockDim.x + threadIdx.x;
    int total = B * NC * 9;
    if (tid >= total) return;
    int e  = tid % 9;
    int bc = tid / 9;
    int c  = bc % NC;
    int b  = bc / NC;
    int t0 = c * L;

    float S_p = (t0 == 0) ? 0.f : Se[((size_t)b * T_LEN + t0 - 1) * 9 + e];

    size_t rbase = (((size_t)b * NMODE) * 9 + (size_t)e) * NC + (size_t)c;
    const size_t rstride = (size_t)9 * NC;

    float Q[NMODE], Pp[NMODE];
    #pragma unroll
    for (int m = 0; m < NMODE; ++m) {
        Q[m]  = PHASE3 ? R[rbase + (size_t)m * rstride] : 0.f;
        Pp[m] = 1.0f;
    }

    const size_t nOut = (size_t)B * T_LEN * 9;

    for (int s = 0; s < L; ++s) {
        size_t row = (size_t)b * T_LEN + (t0 + s);
        const float4* ac = (const float4*)(AC + row * 16);
        float4 a0 = ac[0], a1 = ac[1], c0 = ac[2], c1 = ac[3];

        size_t sidx = row * 9 + (size_t)e;
        float S_c = Se[sidx];
        float dS  = S_c - S_p;
        S_p = S_c;

        Q[0] = a0.x * Q[0] + c0.x * dS;
        Q[1] = a0.y * Q[1] + c0.y * dS;
        Q[2] = a0.z * Q[2] + c0.z * dS;
        Q[3] = a0.w * Q[3] + c0.w * dS;
        Q[4] = a1.x * Q[4] + c1.x * dS;
        Q[5] = a1.y * Q[5] + c1.y * dS;
        Q[6] = a1.z * Q[6] + c1.z * dS;
        Q[7] = a1.w * Q[7] + c1.w * dS;

        if (PHASE3) {
            float qsum = ((Q[0] + Q[1]) + (Q[2] + Q[3]))
                       + ((Q[4] + Q[5]) + (Q[6] + Q[7]));
            float sinf = GI[row] * S_c;
            out[sidx]            = sinf + qsum;  // S
            out[nOut + sidx]     = sinf;         // S_infy
            out[2 * nOut + sidx] = qsum;         // Q_sum
        } else {
            Pp[0] *= a0.x; Pp[1] *= a0.y; Pp[2] *= a0.z; Pp[3] *= a0.w;
            Pp[4] *= a1.x; Pp[5] *= a1.y; Pp[6] *= a1.z; Pp[7] *= a1.w;
        }
    }

    if (!PHASE3) {
        #pragma unroll
        for (int m = 0; m < NMODE; ++m) R[rbase + (size_t)m * rstride] = Q[m];
        if (e == 0) {
            size_t pbase = ((size_t)b * NMODE) * NC + (size_t)c;
            #pragma unroll
            for (int m = 0; m < NMODE; ++m) P[pbase + (size_t)m * NC] = Pp[m];
        }
    }
}

// ---------------------------------------------------------------------------
// Fallback scan (no coeff workspace): recompute coefficients inline.
// Same R/P layout as scan_coeff so chunk_scan is shared.
// ---------------------------------------------------------------------------
template <bool PHASE3>
__global__ __launch_bounds__(256)
void scan_raw(const float* __restrict__ Se,
              const float* __restrict__ tt,
              const float* __restrict__ pp,
              float* __restrict__ R,
              float* __restrict__ P,
              float* __restrict__ out,
              int B, int NC, int L) {
    int tid = blockIdx.x * blockDim.x + threadIdx.x;
    int total = B * NC * 9;
    if (tid >= total) return;
    int e  = tid % 9;
    int bc = tid / 9;
    int c  = bc % NC;
    int b  = bc / NC;
    int t0 = c * L;

    float raw[NPP];
    {
        int prow = (t0 == 0) ? 0 : (t0 - 1);
        const float* p = pp + ((size_t)b * T_LEN + prow) * NPP;
        #pragma unroll
        for (int k = 0; k < NPP; ++k) raw[k] = p[k];
    }
    float gs = 0.f;
    #pragma unroll
    for (int k = 8; k < NPP; ++k) gs += raw[k];
    float inv = __builtin_amdgcn_rcpf(gs);

    float tau_p[NMODE], g_p[NMODE];
    #pragma unroll
    for (int m = 0; m < NMODE; ++m) {
        tau_p[m] = raw[m];
        g_p[m]   = raw[9 + m] * inv;
    }
    float t_p = (t0 == 0) ? -tt[(size_t)b * T_LEN + 1]
                          :  tt[(size_t)b * T_LEN + t0 - 1];
    float S_p = (t0 == 0) ? 0.f
                          : Se[((size_t)b * T_LEN + t0 - 1) * 9 + e];

    size_t rbase = (((size_t)b * NMODE) * 9 + (size_t)e) * NC + (size_t)c;
    const size_t rstride = (size_t)9 * NC;

    float Q[NMODE], Pp[NMODE];
    #pragma unroll
    for (int m = 0; m < NMODE; ++m) {
        Q[m]  = PHASE3 ? R[rbase + (size_t)m * rstride] : 0.f;
        Pp[m] = 1.0f;
    }

    const size_t nOut = (size_t)B * T_LEN * 9;

    for (int s = 0; s < L; ++s) {
        int trow = t0 + s;
        const float* p = pp + ((size_t)b * T_LEN + trow) * NPP;
        #pragma unroll
        for (int k = 0; k < NPP; ++k) raw[k] = p[k];

        float gs2 = 0.f;
        #pragma unroll
        for (int k = 8; k < NPP; ++k) gs2 += raw[k];
        float inv2 = __builtin_amdgcn_rcpf(gs2);

        float t_c = tt[(size_t)b * T_LEN + trow];
        size_t sidx = ((size_t)b * T_LEN + trow) * 9 + (size_t)e;
        float S_c = Se[sidx];

        float dtv = t_c - t_p;
        float dS  = S_c - S_p;
        float mhdt = -0.5f * dtv;

        float qsum = 0.f;
        #pragma unroll
        for (int m = 0; m < NMODE; ++m) {
            float tau_c  = raw[m];
            float g_c    = raw[9 + m] * inv2;
            float tau_b  = 0.5f * (tau_c + tau_p[m]);
            float g_b    = 0.5f * (g_c + g_p[m]);
            float ee     = __expf(mhdt * __builtin_amdgcn_rcpf(tau_b));
            float A      = ee * ee;
            Q[m] = A * Q[m] + (ee * g_b) * dS;
            if (!PHASE3) Pp[m] *= A;
            else         qsum  += Q[m];
            tau_p[m] = tau_c;
            g_p[m]   = g_c;
        }
        t_p = t_c;
        S_p = S_c;

        if (PHASE3) {
            float sinf = (raw[8] * inv2) * S_c;
            out[sidx]            = sinf + qsum;
            out[nOut + sidx]     = sinf;
            out[2 * nOut + sidx] = qsum;
        }
    }

    if (!PHASE3) {
        #pragma unroll
        for (int m = 0; m < NMODE; ++m) R[rbase + (size_t)m * rstride] = Q[m];
        if (e == 0) {
            size_t pbase = ((size_t)b * NMODE) * NC + (size_t)c;
            #pragma unroll
            for (int m = 0; m < NMODE; ++m) P[pbase + (size_t)m * NC] = Pp[m];
        }
    }
}

// ---------------------------------------------------------------------------
// Phase 2: per (b, mode, entry) sequential exclusive scan over NC chunks.
// Contiguous along c -> pipelineable loads.
// ---------------------------------------------------------------------------
__global__ __launch_bounds__(128)
void chunk_scan(float* __restrict__ R, const float* __restrict__ P,
                int B, int NC) {
    int tid = blockIdx.x * blockDim.x + threadIdx.x;
    int total = B * NMODE * 9;
    if (tid >= total) return;
    int e = tid % 9;
    int m = (tid / 9) % NMODE;
    int b = tid / (NMODE * 9);

    float* r = R + (((size_t)b * NMODE + m) * 9 + (size_t)e) * NC;
    const float* p = P + ((size_t)b * NMODE + m) * NC;

    float z = 0.f;
    #pragma unroll 8
    for (int c = 0; c < NC; ++c) {
        float rv = r[c];
        float pv = p[c];
        r[c] = z;
        z = pv * z + rv;
    }
}

extern "C" void kernel_launch(void* const* d_in, const int* in_sizes, int n_in,
                              void* d_out, int out_size, void* d_ws, size_t ws_size,
                              hipStream_t stream) {
    const float* Se = (const float*)d_in[0];
    const float* tt = (const float*)d_in[1];
    const float* pp = (const float*)d_in[2];
    float* out = (float*)d_out;

    int B = in_sizes[1] / T_LEN;

    size_t coeff_f = (size_t)B * T_LEN * 16 + (size_t)B * T_LEN;  // AC + GI

    int NC = 256;
    bool use_coeff = true;
    while (NC > 8) {
        size_t need = (coeff_f + (size_t)B * NC * 72 + (size_t)B * NC * 8) * sizeof(float);
        if (need <= ws_size) break;
        NC >>= 1;
    }
    {
        size_t need = (coeff_f + (size_t)B * NC * 72 + (size_t)B * NC * 8) * sizeof(float);
        if (need > ws_size) {
            use_coeff = false;
            NC = 128;
            while (NC > 1 &&
                   ((size_t)B * NC * 80) * sizeof(float) > ws_size) NC >>= 1;
        }
    }
    int L = T_LEN / NC;

    dim3 blk(256);
    int tot1  = B * NC * 9;
    int grid1 = (tot1 + 255) / 256;
    int tot2  = B * NMODE * 9;
    int grid2 = (tot2 + 127) / 128;

    if (use_coeff) {
        float* AC = (float*)d_ws;
        float* GI = AC + (size_t)B * T_LEN * 16;
        float* R  = GI + (size_t)B * T_LEN;
        float* P  = R  + (size_t)B * NC * 72;

        int totc  = B * T_LEN;
        int gridc = (totc + 255) / 256;
        coeff_kernel<<<gridc, blk, 0, stream>>>(tt, pp, AC, GI, B);
        scan_coeff<false><<<grid1, blk, 0, stream>>>(Se, AC, GI, R, P, nullptr, B, NC, L);
        chunk_scan<<<grid2, dim3(128), 0, stream>>>(R, P, B, NC);
        scan_coeff<true><<<grid1, blk, 0, stream>>>(Se, AC, GI, R, P, out, B, NC, L);
    } else {
        float* R = (float*)d_ws;
        float* P = R + (size_t)B * NC * 72;
        scan_raw<false><<<grid1, blk, 0, stream>>>(Se, tt, pp, R, P, nullptr, B, NC, L);
        chunk_scan<<<grid2, dim3(128), 0, stream>>>(R, P, B, NC);
        scan_raw<true><<<grid1, blk, 0, stream>>>(Se, tt, pp, R, P, out, B, NC, L);
    }
}